// Round 11
// baseline (103.636 us; speedup 1.0000x reference)
//
#include <hip/hip_runtime.h>

typedef __attribute__((ext_vector_type(8))) short short8;
typedef __attribute__((ext_vector_type(4))) float f32x4;

// Native __bf16 cast -> hardware cvt (RNE).
__device__ __forceinline__ short f2bf(float f) {
    __bf16 h = (__bf16)f;
    return (short)__builtin_bit_cast(unsigned short, h);
}

__device__ __forceinline__ float fast_tanh(float x) {
    float e2 = __expf(2.f * x);
    return 1.f - 2.f * __builtin_amdgcn_rcpf(e2 + 1.f);
}

__device__ __forceinline__ float fast_sigmoid(float x) {
    return __builtin_amdgcn_rcpf(1.f + __expf(-x));
}

// DIAGNOSTIC (R11): canonical streaming-read probe. Grid-stride float4
// read-reduce over enc; measures the machine's COLD pure-read HBM rate in
// this harness state (L3 flushed+dirtied by 1GB poison fill). Runs FIRST.
// Results kept live via workspace writes (no DCE). Deterministic.
__global__ __launch_bounds__(256) void probe_kernel(
        const float4* __restrict__ enc4, float* __restrict__ out_ws, int n4) {
    const int gid    = blockIdx.x * 256 + threadIdx.x;
    const int stride = gridDim.x * 256;
    float4 a0 = make_float4(0.f, 0.f, 0.f, 0.f);
    float4 a1 = make_float4(0.f, 0.f, 0.f, 0.f);
    float4 a2 = make_float4(0.f, 0.f, 0.f, 0.f);
    float4 a3 = make_float4(0.f, 0.f, 0.f, 0.f);
    for (int i = gid; i + 3 * stride < n4; i += 4 * stride) {
        float4 v0 = enc4[i];
        float4 v1 = enc4[i + stride];
        float4 v2 = enc4[i + 2 * stride];
        float4 v3 = enc4[i + 3 * stride];
        a0.x += v0.x; a0.y += v0.y; a0.z += v0.z; a0.w += v0.w;
        a1.x += v1.x; a1.y += v1.y; a1.z += v1.z; a1.w += v1.w;
        a2.x += v2.x; a2.y += v2.y; a2.z += v2.z; a2.w += v2.w;
        a3.x += v3.x; a3.y += v3.y; a3.z += v3.z; a3.w += v3.w;
    }
    out_ws[gid] = (a0.x + a0.y + a0.z + a0.w) + (a1.x + a1.y + a1.z + a1.w)
                + (a2.x + a2.y + a2.z + a2.w) + (a3.x + a3.y + a3.z + a3.w);
}

// Kernel 1 (== R7/R10 best): swapped-MFMA, NS=16, depth-2, block-contiguous.
__global__ __launch_bounds__(256, 2) void attn_kernel(
        const float* __restrict__ enc, const float* __restrict__ s_in,
        const float* __restrict__ W_attn, const float* __restrict__ b_attn,
        const float* __restrict__ v_attn,
        float* __restrict__ ctx_part, float* __restrict__ l_part,
        int NS, int chunk) {
    const int tid  = threadIdx.x;
    const int lane = tid & 63;
    const int w    = tid >> 6;                 // wave in block
    const int cid  = blockIdx.x % NS;          // S-chunk (shared by all 4 waves)
    const int btile = (blockIdx.x / NS) * 4 + w;  // 4 adjacent btiles per block
    const int b0 = btile * 16;
    const int lo = lane & 15;   // batch (B-frag col / D col)
    const int g  = lane >> 4;   // k-group; D rows d = 4g+j (+16t)

    short8 bW2[2][2];           // A-frag: W_attn[16t+lo][32+32cc+8g+e]
    f32x4 spre[2];
    float v0[4], v1[4];
    {
        const float* sp = s_in + (size_t)(b0 + lo) * 32 + 8 * g;
        float4 sa = *(const float4*)sp;
        float4 sb = *(const float4*)(sp + 4);
        short8 aS;                      // B-frag: s[b0+lo][8g+e]
        aS[0]=f2bf(sa.x); aS[1]=f2bf(sa.y); aS[2]=f2bf(sa.z); aS[3]=f2bf(sa.w);
        aS[4]=f2bf(sb.x); aS[5]=f2bf(sb.y); aS[6]=f2bf(sb.z); aS[7]=f2bf(sb.w);
#pragma unroll
        for (int t = 0; t < 2; ++t) {
            const float* wp = W_attn + (size_t)(16*t + lo) * 96 + 8 * g;
            float4 wa = *(const float4*)wp;
            float4 wb = *(const float4*)(wp + 4);
            short8 bW1;                 // A-frag: W_attn[16t+lo][8g+e]
            bW1[0]=f2bf(wa.x); bW1[1]=f2bf(wa.y); bW1[2]=f2bf(wa.z); bW1[3]=f2bf(wa.w);
            bW1[4]=f2bf(wb.x); bW1[5]=f2bf(wb.y); bW1[6]=f2bf(wb.z); bW1[7]=f2bf(wb.w);
            f32x4 ci;                   // seed at row d = 16t + 4g + j
#pragma unroll
            for (int j = 0; j < 4; ++j) ci[j] = b_attn[16*t + 4*g + j];
            spre[t] = __builtin_amdgcn_mfma_f32_16x16x32_bf16(bW1, aS, ci, 0, 0, 0);
#pragma unroll
            for (int cc = 0; cc < 2; ++cc) {
                const float* qp = W_attn + (size_t)(16*t + lo) * 96 + 32 + 32*cc + 8*g;
                float4 qa = *(const float4*)qp;
                float4 qb = *(const float4*)(qp + 4);
                short8 bb;
                bb[0]=f2bf(qa.x); bb[1]=f2bf(qa.y); bb[2]=f2bf(qa.z); bb[3]=f2bf(qa.w);
                bb[4]=f2bf(qb.x); bb[5]=f2bf(qb.y); bb[6]=f2bf(qb.z); bb[7]=f2bf(qb.w);
                bW2[t][cc] = bb;
            }
        }
#pragma unroll
        for (int j = 0; j < 4; ++j) { v0[j] = v_attn[4*g + j]; v1[j] = v_attn[16 + 4*g + j]; }
    }

    float ctx[16];
#pragma unroll
    for (int i = 0; i < 16; ++i) ctx[i] = 0.f;
    float l_acc = 0.f;

    const size_t rowstride = (size_t)2048 * 64;
    const float* pc = enc + (size_t)(cid * chunk) * rowstride + (size_t)(b0 + lo) * 64 + 8 * g;

    float4 c0a,c0b,c1a,c1b, n0a,n0b,n1a,n1b;
#define LOAD_ENC(P, A,Bq,C,D) { const float4* q = (const float4*)(P); A = q[0]; Bq = q[1]; C = q[8]; D = q[9]; }

#define BODY(A,Bq,C,D) { \
    short8 a0, a1; \
    a0[0]=f2bf(A.x); a0[1]=f2bf(A.y); a0[2]=f2bf(A.z); a0[3]=f2bf(A.w); \
    a0[4]=f2bf(Bq.x); a0[5]=f2bf(Bq.y); a0[6]=f2bf(Bq.z); a0[7]=f2bf(Bq.w); \
    a1[0]=f2bf(C.x); a1[1]=f2bf(C.y); a1[2]=f2bf(C.z); a1[3]=f2bf(C.w); \
    a1[4]=f2bf(D.x); a1[5]=f2bf(D.y); a1[6]=f2bf(D.z); a1[7]=f2bf(D.w); \
    f32x4 acc0 = __builtin_amdgcn_mfma_f32_16x16x32_bf16(bW2[0][0], a0, spre[0], 0,0,0); \
    acc0 = __builtin_amdgcn_mfma_f32_16x16x32_bf16(bW2[0][1], a1, acc0, 0,0,0); \
    f32x4 acc1 = __builtin_amdgcn_mfma_f32_16x16x32_bf16(bW2[1][0], a0, spre[1], 0,0,0); \
    acc1 = __builtin_amdgcn_mfma_f32_16x16x32_bf16(bW2[1][1], a1, acc1, 0,0,0); \
    float part = fast_tanh(acc0[0])*v0[0] + fast_tanh(acc0[1])*v0[1] \
               + fast_tanh(acc0[2])*v0[2] + fast_tanh(acc0[3])*v0[3] \
               + fast_tanh(acc1[0])*v1[0] + fast_tanh(acc1[1])*v1[1] \
               + fast_tanh(acc1[2])*v1[2] + fast_tanh(acc1[3])*v1[3]; \
    part += __shfl_xor(part, 16); \
    part += __shfl_xor(part, 32); \
    float w_ = __expf(part); \
    l_acc += w_; \
    ctx[0] += w_*A.x;  ctx[1] += w_*A.y;  ctx[2] += w_*A.z;  ctx[3] += w_*A.w; \
    ctx[4] += w_*Bq.x; ctx[5] += w_*Bq.y; ctx[6] += w_*Bq.z; ctx[7] += w_*Bq.w; \
    ctx[8] += w_*C.x;  ctx[9] += w_*C.y;  ctx[10] += w_*C.z; ctx[11] += w_*C.w; \
    ctx[12] += w_*D.x; ctx[13] += w_*D.y; ctx[14] += w_*D.z; ctx[15] += w_*D.w; \
}

    LOAD_ENC(pc, c0a, c0b, c1a, c1b);
    for (int i = 0; i < chunk; i += 2) {
        LOAD_ENC(pc + rowstride, n0a, n0b, n1a, n1b);
        BODY(c0a, c0b, c1a, c1b);
        if (i + 2 < chunk) { LOAD_ENC(pc + 2*rowstride, c0a, c0b, c1a, c1b); }
        BODY(n0a, n0b, n1a, n1b);
        pc += 2 * rowstride;
    }
#undef BODY
#undef LOAD_ENC

    float* cp = ctx_part + (size_t)(cid * 2048 + b0 + lo) * 64 + 8 * g;
    *(float4*)(cp)      = make_float4(ctx[0],  ctx[1],  ctx[2],  ctx[3]);
    *(float4*)(cp + 4)  = make_float4(ctx[4],  ctx[5],  ctx[6],  ctx[7]);
    *(float4*)(cp + 32) = make_float4(ctx[8],  ctx[9],  ctx[10], ctx[11]);
    *(float4*)(cp + 36) = make_float4(ctx[12], ctx[13], ctx[14], ctx[15]);
    if (lane < 16) l_part[cid * 2048 + b0 + lane] = l_acc;
}

// Kernel 2: reduce partials -> ctx, then emb + GRU + fc (R10 unrolled reduce).
__global__ __launch_bounds__(256) void finish_kernel(
        const float* __restrict__ dec_in, const float* __restrict__ s_in,
        const float* __restrict__ W_emb, const float* __restrict__ b_emb,
        const float* __restrict__ W_ih, const float* __restrict__ W_hh,
        const float* __restrict__ b_ih, const float* __restrict__ b_hh,
        const float* __restrict__ W_fc, const float* __restrict__ b_fc,
        const float* __restrict__ ctx_part, const float* __restrict__ l_part,
        float* __restrict__ out, int NS) {
    __shared__ __align__(16) float x_lds[8][80];   // [emb(16); ctx(64)]
    __shared__ __align__(16) float s_lds[8][32];
    const int tid = threadIdx.x;
    const int bl = tid >> 5;
    const int h  = tid & 31;
    const int b  = blockIdx.x * 8 + bl;

    float c0a = 0.f, c0b = 0.f, c0c = 0.f, c0d = 0.f;
    float c1a = 0.f, c1b = 0.f, c1c = 0.f, c1d = 0.f;
    float lsa = 0.f, lsb = 0.f, lsc = 0.f, lsd = 0.f;
    for (int c = 0; c < NS; c += 4) {
        const float* p0 = ctx_part + (size_t)((c+0) * 2048 + b) * 64;
        const float* p1 = ctx_part + (size_t)((c+1) * 2048 + b) * 64;
        const float* p2 = ctx_part + (size_t)((c+2) * 2048 + b) * 64;
        const float* p3 = ctx_part + (size_t)((c+3) * 2048 + b) * 64;
        c0a += p0[h];      c0b += p1[h];      c0c += p2[h];      c0d += p3[h];
        c1a += p0[h + 32]; c1b += p1[h + 32]; c1c += p2[h + 32]; c1d += p3[h + 32];
        lsa += l_part[(c+0) * 2048 + b]; lsb += l_part[(c+1) * 2048 + b];
        lsc += l_part[(c+2) * 2048 + b]; lsd += l_part[(c+3) * 2048 + b];
    }
    float c0 = (c0a + c0b) + (c0c + c0d);
    float c1 = (c1a + c1b) + (c1c + c1d);
    float ls = (lsa + lsb) + (lsc + lsd);
    float inv = 1.f / ls;
    x_lds[bl][16 + h] = c0 * inv;
    x_lds[bl][48 + h] = c1 * inv;
    if (h < 16) x_lds[bl][h] = fmaxf(0.f, dec_in[b] * W_emb[h] + b_emb[h]);
    s_lds[bl][h] = s_in[b * 32 + h];
    __syncthreads();

    float a_r  = b_ih[h]      + b_hh[h];
    float a_z  = b_ih[32 + h] + b_hh[32 + h];
    float gi_n = b_ih[64 + h];
    float gh_n = b_hh[64 + h];
    const float4* xv4 = (const float4*)&x_lds[bl][0];
    const float4* wr4 = (const float4*)(W_ih + 80 * h);
    const float4* wz4 = (const float4*)(W_ih + 80 * (32 + h));
    const float4* wn4 = (const float4*)(W_ih + 80 * (64 + h));
#pragma unroll
    for (int j = 0; j < 20; ++j) {
        float4 x = xv4[j], wr = wr4[j], wz = wz4[j], wn = wn4[j];
        a_r  += x.x*wr.x + x.y*wr.y + x.z*wr.z + x.w*wr.w;
        a_z  += x.x*wz.x + x.y*wz.y + x.z*wz.z + x.w*wz.w;
        gi_n += x.x*wn.x + x.y*wn.y + x.z*wn.z + x.w*wn.w;
    }
    const float4* sv4 = (const float4*)&s_lds[bl][0];
    const float4* hr4 = (const float4*)(W_hh + 32 * h);
    const float4* hz4 = (const float4*)(W_hh + 32 * (32 + h));
    const float4* hn4 = (const float4*)(W_hh + 32 * (64 + h));
#pragma unroll
    for (int j = 0; j < 8; ++j) {
        float4 x = sv4[j], wr = hr4[j], wz = hz4[j], wn = hn4[j];
        a_r  += x.x*wr.x + x.y*wr.y + x.z*wr.z + x.w*wr.w;
        a_z  += x.x*wz.x + x.y*wz.y + x.z*wz.z + x.w*wz.w;
        gh_n += x.x*wn.x + x.y*wn.y + x.z*wn.z + x.w*wn.w;
    }
    float r = fast_sigmoid(a_r);
    float z = fast_sigmoid(a_z);
    float n = fast_tanh(gi_n + r * gh_n);
    float sv = s_lds[bl][h];
    float hn = (1.f - z) * n + z * sv;
    out[2048 + b * 32 + h] = hn;

    float p = hn * W_fc[h] + x_lds[bl][16 + h] * W_fc[32 + h] + x_lds[bl][48 + h] * W_fc[64 + h];
    if (h < 16) p += x_lds[bl][h] * W_fc[96 + h];
    p += __shfl_xor(p, 1); p += __shfl_xor(p, 2); p += __shfl_xor(p, 4);
    p += __shfl_xor(p, 8); p += __shfl_xor(p, 16);
    if (h == 0) out[b] = p + b_fc[0];
}

extern "C" void kernel_launch(void* const* d_in, const int* in_sizes, int n_in,
                              void* d_out, int out_size, void* d_ws, size_t ws_size,
                              hipStream_t stream) {
    const float* dec_in = (const float*)d_in[0];
    const float* s_in   = (const float*)d_in[1];
    const float* enc    = (const float*)d_in[2];
    const float* W_attn = (const float*)d_in[3];
    const float* b_attn = (const float*)d_in[4];
    const float* v_attn = (const float*)d_in[5];
    const float* W_emb  = (const float*)d_in[6];
    const float* b_emb  = (const float*)d_in[7];
    const float* W_ih   = (const float*)d_in[8];
    const float* W_hh   = (const float*)d_in[9];
    const float* b_ih   = (const float*)d_in[10];
    const float* b_hh   = (const float*)d_in[11];
    const float* W_fc   = (const float*)d_in[12];
    const float* b_fc   = (const float*)d_in[13];
    float* out = (float*)d_out;

    int NS = 16;
    while (NS > 4 && (size_t)NS * (2048u * 64u + 2048u) * sizeof(float) > ws_size) NS >>= 1;
    int chunk = 512 / NS;
    float* ctx_part = (float*)d_ws;                       // [NS][2048][64]
    float* l_part   = ctx_part + (size_t)NS * 2048 * 64;  // [NS][2048]
    float* probe_out = l_part + (size_t)NS * 2048;        // [524288] floats (2MB)

    // DIAGNOSTIC: cold pure-read ceiling probe (runs first; attn semi-warm).
    const int n4 = 512 * 2048 * 64 / 4;
    probe_kernel<<<dim3(2048), dim3(256), 0, stream>>>(
        (const float4*)enc, probe_out, n4);

    attn_kernel<<<dim3(32 * NS), dim3(256), 0, stream>>>(
        enc, s_in, W_attn, b_attn, v_attn, ctx_part, l_part, NS, chunk);
    finish_kernel<<<dim3(256), dim3(256), 0, stream>>>(
        dec_in, s_in, W_emb, b_emb, W_ih, W_hh, b_ih, b_hh, W_fc, b_fc,
        ctx_part, l_part, out, NS);
}

// Round 12
// 58.484 us; speedup vs baseline: 1.7720x; 1.7720x over previous
//
#include <hip/hip_runtime.h>

typedef __attribute__((ext_vector_type(8))) short short8;
typedef __attribute__((ext_vector_type(4))) float f32x4;

// Native __bf16 cast -> hardware cvt (RNE).
__device__ __forceinline__ short f2bf(float f) {
    __bf16 h = (__bf16)f;
    return (short)__builtin_bit_cast(unsigned short, h);
}

__device__ __forceinline__ float fast_tanh(float x) {
    float e2 = __expf(2.f * x);
    return 1.f - 2.f * __builtin_amdgcn_rcpf(e2 + 1.f);
}

__device__ __forceinline__ float fast_sigmoid(float x) {
    return __builtin_amdgcn_rcpf(1.f + __expf(-x));
}

// Kernel 1 (session best, 58.5us total): swapped-MFMA, NS=16, depth-2,
// block-contiguous btile mapping. At the cold-read memory roofline:
// R11 probe measured the canonical float4 streaming read at ~4.7-4.9 TB/s
// in this harness state (L3 flushed+dirtied by 1GB poison fill per replay);
// attn reads 268.4MB at exactly that rate. Bytes are irreducible.
__global__ __launch_bounds__(256, 2) void attn_kernel(
        const float* __restrict__ enc, const float* __restrict__ s_in,
        const float* __restrict__ W_attn, const float* __restrict__ b_attn,
        const float* __restrict__ v_attn,
        float* __restrict__ ctx_part, float* __restrict__ l_part,
        int NS, int chunk) {
    const int tid  = threadIdx.x;
    const int lane = tid & 63;
    const int w    = tid >> 6;                 // wave in block
    const int cid  = blockIdx.x % NS;          // S-chunk (shared by all 4 waves)
    const int btile = (blockIdx.x / NS) * 4 + w;  // 4 adjacent btiles per block
    const int b0 = btile * 16;
    const int lo = lane & 15;   // batch (B-frag col / D col)
    const int g  = lane >> 4;   // k-group; D rows d = 4g+j (+16t)

    short8 bW2[2][2];           // A-frag: W_attn[16t+lo][32+32cc+8g+e]
    f32x4 spre[2];
    float v0[4], v1[4];
    {
        const float* sp = s_in + (size_t)(b0 + lo) * 32 + 8 * g;
        float4 sa = *(const float4*)sp;
        float4 sb = *(const float4*)(sp + 4);
        short8 aS;                      // B-frag: s[b0+lo][8g+e]
        aS[0]=f2bf(sa.x); aS[1]=f2bf(sa.y); aS[2]=f2bf(sa.z); aS[3]=f2bf(sa.w);
        aS[4]=f2bf(sb.x); aS[5]=f2bf(sb.y); aS[6]=f2bf(sb.z); aS[7]=f2bf(sb.w);
#pragma unroll
        for (int t = 0; t < 2; ++t) {
            const float* wp = W_attn + (size_t)(16*t + lo) * 96 + 8 * g;
            float4 wa = *(const float4*)wp;
            float4 wb = *(const float4*)(wp + 4);
            short8 bW1;                 // A-frag: W_attn[16t+lo][8g+e]
            bW1[0]=f2bf(wa.x); bW1[1]=f2bf(wa.y); bW1[2]=f2bf(wa.z); bW1[3]=f2bf(wa.w);
            bW1[4]=f2bf(wb.x); bW1[5]=f2bf(wb.y); bW1[6]=f2bf(wb.z); bW1[7]=f2bf(wb.w);
            f32x4 ci;                   // seed at row d = 16t + 4g + j
#pragma unroll
            for (int j = 0; j < 4; ++j) ci[j] = b_attn[16*t + 4*g + j];
            spre[t] = __builtin_amdgcn_mfma_f32_16x16x32_bf16(bW1, aS, ci, 0, 0, 0);
#pragma unroll
            for (int cc = 0; cc < 2; ++cc) {
                const float* qp = W_attn + (size_t)(16*t + lo) * 96 + 32 + 32*cc + 8*g;
                float4 qa = *(const float4*)qp;
                float4 qb = *(const float4*)(qp + 4);
                short8 bb;
                bb[0]=f2bf(qa.x); bb[1]=f2bf(qa.y); bb[2]=f2bf(qa.z); bb[3]=f2bf(qa.w);
                bb[4]=f2bf(qb.x); bb[5]=f2bf(qb.y); bb[6]=f2bf(qb.z); bb[7]=f2bf(qb.w);
                bW2[t][cc] = bb;
            }
        }
#pragma unroll
        for (int j = 0; j < 4; ++j) { v0[j] = v_attn[4*g + j]; v1[j] = v_attn[16 + 4*g + j]; }
    }

    float ctx[16];
#pragma unroll
    for (int i = 0; i < 16; ++i) ctx[i] = 0.f;
    float l_acc = 0.f;

    const size_t rowstride = (size_t)2048 * 64;
    const float* pc = enc + (size_t)(cid * chunk) * rowstride + (size_t)(b0 + lo) * 64 + 8 * g;

    float4 c0a,c0b,c1a,c1b, n0a,n0b,n1a,n1b;
#define LOAD_ENC(P, A,Bq,C,D) { const float4* q = (const float4*)(P); A = q[0]; Bq = q[1]; C = q[8]; D = q[9]; }

#define BODY(A,Bq,C,D) { \
    short8 a0, a1; \
    a0[0]=f2bf(A.x); a0[1]=f2bf(A.y); a0[2]=f2bf(A.z); a0[3]=f2bf(A.w); \
    a0[4]=f2bf(Bq.x); a0[5]=f2bf(Bq.y); a0[6]=f2bf(Bq.z); a0[7]=f2bf(Bq.w); \
    a1[0]=f2bf(C.x); a1[1]=f2bf(C.y); a1[2]=f2bf(C.z); a1[3]=f2bf(C.w); \
    a1[4]=f2bf(D.x); a1[5]=f2bf(D.y); a1[6]=f2bf(D.z); a1[7]=f2bf(D.w); \
    f32x4 acc0 = __builtin_amdgcn_mfma_f32_16x16x32_bf16(bW2[0][0], a0, spre[0], 0,0,0); \
    acc0 = __builtin_amdgcn_mfma_f32_16x16x32_bf16(bW2[0][1], a1, acc0, 0,0,0); \
    f32x4 acc1 = __builtin_amdgcn_mfma_f32_16x16x32_bf16(bW2[1][0], a0, spre[1], 0,0,0); \
    acc1 = __builtin_amdgcn_mfma_f32_16x16x32_bf16(bW2[1][1], a1, acc1, 0,0,0); \
    float part = fast_tanh(acc0[0])*v0[0] + fast_tanh(acc0[1])*v0[1] \
               + fast_tanh(acc0[2])*v0[2] + fast_tanh(acc0[3])*v0[3] \
               + fast_tanh(acc1[0])*v1[0] + fast_tanh(acc1[1])*v1[1] \
               + fast_tanh(acc1[2])*v1[2] + fast_tanh(acc1[3])*v1[3]; \
    part += __shfl_xor(part, 16); \
    part += __shfl_xor(part, 32); \
    float w_ = __expf(part); \
    l_acc += w_; \
    ctx[0] += w_*A.x;  ctx[1] += w_*A.y;  ctx[2] += w_*A.z;  ctx[3] += w_*A.w; \
    ctx[4] += w_*Bq.x; ctx[5] += w_*Bq.y; ctx[6] += w_*Bq.z; ctx[7] += w_*Bq.w; \
    ctx[8] += w_*C.x;  ctx[9] += w_*C.y;  ctx[10] += w_*C.z; ctx[11] += w_*C.w; \
    ctx[12] += w_*D.x; ctx[13] += w_*D.y; ctx[14] += w_*D.z; ctx[15] += w_*D.w; \
}

    LOAD_ENC(pc, c0a, c0b, c1a, c1b);
    for (int i = 0; i < chunk; i += 2) {
        LOAD_ENC(pc + rowstride, n0a, n0b, n1a, n1b);
        BODY(c0a, c0b, c1a, c1b);
        if (i + 2 < chunk) { LOAD_ENC(pc + 2*rowstride, c0a, c0b, c1a, c1b); }
        BODY(n0a, n0b, n1a, n1b);
        pc += 2 * rowstride;
    }
#undef BODY
#undef LOAD_ENC

    float* cp = ctx_part + (size_t)(cid * 2048 + b0 + lo) * 64 + 8 * g;
    *(float4*)(cp)      = make_float4(ctx[0],  ctx[1],  ctx[2],  ctx[3]);
    *(float4*)(cp + 4)  = make_float4(ctx[4],  ctx[5],  ctx[6],  ctx[7]);
    *(float4*)(cp + 32) = make_float4(ctx[8],  ctx[9],  ctx[10], ctx[11]);
    *(float4*)(cp + 36) = make_float4(ctx[12], ctx[13], ctx[14], ctx[15]);
    if (lane < 16) l_part[cid * 2048 + b0 + lane] = l_acc;
}

// Kernel 2: reduce partials -> ctx, then emb + GRU + fc (unrolled x4 reduce).
__global__ __launch_bounds__(256) void finish_kernel(
        const float* __restrict__ dec_in, const float* __restrict__ s_in,
        const float* __restrict__ W_emb, const float* __restrict__ b_emb,
        const float* __restrict__ W_ih, const float* __restrict__ W_hh,
        const float* __restrict__ b_ih, const float* __restrict__ b_hh,
        const float* __restrict__ W_fc, const float* __restrict__ b_fc,
        const float* __restrict__ ctx_part, const float* __restrict__ l_part,
        float* __restrict__ out, int NS) {
    __shared__ __align__(16) float x_lds[8][80];   // [emb(16); ctx(64)]
    __shared__ __align__(16) float s_lds[8][32];
    const int tid = threadIdx.x;
    const int bl = tid >> 5;
    const int h  = tid & 31;
    const int b  = blockIdx.x * 8 + bl;

    float c0a = 0.f, c0b = 0.f, c0c = 0.f, c0d = 0.f;
    float c1a = 0.f, c1b = 0.f, c1c = 0.f, c1d = 0.f;
    float lsa = 0.f, lsb = 0.f, lsc = 0.f, lsd = 0.f;
    for (int c = 0; c < NS; c += 4) {
        const float* p0 = ctx_part + (size_t)((c+0) * 2048 + b) * 64;
        const float* p1 = ctx_part + (size_t)((c+1) * 2048 + b) * 64;
        const float* p2 = ctx_part + (size_t)((c+2) * 2048 + b) * 64;
        const float* p3 = ctx_part + (size_t)((c+3) * 2048 + b) * 64;
        c0a += p0[h];      c0b += p1[h];      c0c += p2[h];      c0d += p3[h];
        c1a += p0[h + 32]; c1b += p1[h + 32]; c1c += p2[h + 32]; c1d += p3[h + 32];
        lsa += l_part[(c+0) * 2048 + b]; lsb += l_part[(c+1) * 2048 + b];
        lsc += l_part[(c+2) * 2048 + b]; lsd += l_part[(c+3) * 2048 + b];
    }
    float c0 = (c0a + c0b) + (c0c + c0d);
    float c1 = (c1a + c1b) + (c1c + c1d);
    float ls = (lsa + lsb) + (lsc + lsd);
    float inv = 1.f / ls;
    x_lds[bl][16 + h] = c0 * inv;
    x_lds[bl][48 + h] = c1 * inv;
    if (h < 16) x_lds[bl][h] = fmaxf(0.f, dec_in[b] * W_emb[h] + b_emb[h]);
    s_lds[bl][h] = s_in[b * 32 + h];
    __syncthreads();

    float a_r  = b_ih[h]      + b_hh[h];
    float a_z  = b_ih[32 + h] + b_hh[32 + h];
    float gi_n = b_ih[64 + h];
    float gh_n = b_hh[64 + h];
    const float4* xv4 = (const float4*)&x_lds[bl][0];
    const float4* wr4 = (const float4*)(W_ih + 80 * h);
    const float4* wz4 = (const float4*)(W_ih + 80 * (32 + h));
    const float4* wn4 = (const float4*)(W_ih + 80 * (64 + h));
#pragma unroll
    for (int j = 0; j < 20; ++j) {
        float4 x = xv4[j], wr = wr4[j], wz = wz4[j], wn = wn4[j];
        a_r  += x.x*wr.x + x.y*wr.y + x.z*wr.z + x.w*wr.w;
        a_z  += x.x*wz.x + x.y*wz.y + x.z*wz.z + x.w*wz.w;
        gi_n += x.x*wn.x + x.y*wn.y + x.z*wn.z + x.w*wn.w;
    }
    const float4* sv4 = (const float4*)&s_lds[bl][0];
    const float4* hr4 = (const float4*)(W_hh + 32 * h);
    const float4* hz4 = (const float4*)(W_hh + 32 * (32 + h));
    const float4* hn4 = (const float4*)(W_hh + 32 * (64 + h));
#pragma unroll
    for (int j = 0; j < 8; ++j) {
        float4 x = sv4[j], wr = hr4[j], wz = hz4[j], wn = hn4[j];
        a_r  += x.x*wr.x + x.y*wr.y + x.z*wr.z + x.w*wr.w;
        a_z  += x.x*wz.x + x.y*wz.y + x.z*wz.z + x.w*wz.w;
        gh_n += x.x*wn.x + x.y*wn.y + x.z*wn.z + x.w*wn.w;
    }
    float r = fast_sigmoid(a_r);
    float z = fast_sigmoid(a_z);
    float n = fast_tanh(gi_n + r * gh_n);
    float sv = s_lds[bl][h];
    float hn = (1.f - z) * n + z * sv;
    out[2048 + b * 32 + h] = hn;

    float p = hn * W_fc[h] + x_lds[bl][16 + h] * W_fc[32 + h] + x_lds[bl][48 + h] * W_fc[64 + h];
    if (h < 16) p += x_lds[bl][h] * W_fc[96 + h];
    p += __shfl_xor(p, 1); p += __shfl_xor(p, 2); p += __shfl_xor(p, 4);
    p += __shfl_xor(p, 8); p += __shfl_xor(p, 16);
    if (h == 0) out[b] = p + b_fc[0];
}

extern "C" void kernel_launch(void* const* d_in, const int* in_sizes, int n_in,
                              void* d_out, int out_size, void* d_ws, size_t ws_size,
                              hipStream_t stream) {
    const float* dec_in = (const float*)d_in[0];
    const float* s_in   = (const float*)d_in[1];
    const float* enc    = (const float*)d_in[2];
    const float* W_attn = (const float*)d_in[3];
    const float* b_attn = (const float*)d_in[4];
    const float* v_attn = (const float*)d_in[5];
    const float* W_emb  = (const float*)d_in[6];
    const float* b_emb  = (const float*)d_in[7];
    const float* W_ih   = (const float*)d_in[8];
    const float* W_hh   = (const float*)d_in[9];
    const float* b_ih   = (const float*)d_in[10];
    const float* b_hh   = (const float*)d_in[11];
    const float* W_fc   = (const float*)d_in[12];
    const float* b_fc   = (const float*)d_in[13];
    float* out = (float*)d_out;

    int NS = 16;
    while (NS > 4 && (size_t)NS * (2048u * 64u + 2048u) * sizeof(float) > ws_size) NS >>= 1;
    int chunk = 512 / NS;
    float* ctx_part = (float*)d_ws;                       // [NS][2048][64]
    float* l_part   = ctx_part + (size_t)NS * 2048 * 64;  // [NS][2048]

    attn_kernel<<<dim3(32 * NS), dim3(256), 0, stream>>>(
        enc, s_in, W_attn, b_attn, v_attn, ctx_part, l_part, NS, chunk);
    finish_kernel<<<dim3(256), dim3(256), 0, stream>>>(
        dec_in, s_in, W_emb, b_emb, W_ih, W_hh, b_ih, b_hh, W_fc, b_fc,
        ctx_part, l_part, out, NS);
}